// Round 8
// baseline (374.362 us; speedup 1.0000x reference)
//
#include <hip/hip_runtime.h>
#include <hip/hip_bf16.h>
#include <stdint.h>

#define M_ROWS 4096
#define N_REFS 32768
#define DIM    512
#define NSPLIT 32
#define BM     128
#define CHUNK  128
#define SLICE  (N_REFS / NSPLIT)   // 1024
#define NCHUNKS (SLICE / CHUNK)    // 8
#define NKT    (DIM / 64)          // 8 K-tiles of BK=64 per chunk

typedef __attribute__((ext_vector_type(8))) short short8;
typedef __attribute__((ext_vector_type(4))) float f32x4;

__device__ __forceinline__ uint32_t f2bf1(float f) {
  uint32_t u = __float_as_uint(f);
  return (u + 0x7FFFu + ((u >> 16) & 1u)) >> 16;   // RNE fp32 -> bf16
}

__global__ void prep_rows(const float* __restrict__ src, uint16_t* __restrict__ dst,
                          float* __restrict__ sq) {
  int row = blockIdx.x;
  int t = threadIdx.x;                       // 256 threads, 2 elems each
  const float2* s = (const float2*)(src + (size_t)row * DIM);
  float2 v = s[t];
  uint32_t packed = f2bf1(v.x) | (f2bf1(v.y) << 16);
  ((uint32_t*)(dst + (size_t)row * DIM))[t] = packed;
  float ss = v.x * v.x + v.y * v.y;
  #pragma unroll
  for (int d = 32; d >= 1; d >>= 1) ss += __shfl_down(ss, d, 64);
  __shared__ float wsum[4];
  int w = t >> 6, lane = t & 63;
  if (lane == 0) wsum[w] = ss;
  __syncthreads();
  if (t == 0) sq[row] = wsum[0] + wsum[1] + wsum[2] + wsum[3];
}

// R3 skeleton with ONE structural change: A-fragments load global->VGPR
// directly (x is 4MB, L2-resident; fragment layout row=l15 / k-group=l4 is a
// contiguous 16B global load). This halves LDS-pipe traffic (the measured
// bottleneck: 24 LDS ops/wave-K-tile ~ 288cyc vs 154cyc MFMA in R1-R7).
// B stays LDS-staged with the verified zero-conflict swizzle.
__global__ __launch_bounds__(256, 2) void ask_main(
    const uint16_t* __restrict__ xbf, const uint16_t* __restrict__ rbf,
    const float* __restrict__ x2, const float* __restrict__ r2,
    const int* __restrict__ y, const int* __restrict__ yref,
    float* __restrict__ totG, float* __restrict__ matchG)
{
  __shared__ unsigned char sB[16384];          // B tile only: 128 x 128B

  const int tid  = threadIdx.x;
  const int w    = tid >> 6, lane = tid & 63;
  const int wr   = w >> 1,  wc   = w & 1;
  const int l15  = lane & 15, l4 = lane >> 4;

  // XCD swizzle (grid 1024, mtile fastest within an XCD chunk): B-slice is
  // shared by 4 consecutive blocks on the same XCD; A panel (512KB) stays hot.
  const int wg    = blockIdx.x;
  const int c     = wg >> 3;
  const int mtile = (wg & 7) * 4 + (c & 3);    // 0..31
  const int nsl   = c >> 2;                    // 0..31
  const int bm       = mtile * BM;
  const int colstart = nsl * SLICE;

  // ---- B staging (R3-verified): row = w*8 + lane>>3 (+c*32), pre-swizzled col
  const int srow = w * 8 + (lane >> 3);
  const int scol = ((lane & 7) ^ ((lane >> 3) & 7)) * 8;

  // ---- B fragment read offsets (R3-verified swizzle) ----
  const int xorv  = (lane & 7) << 4;
  const int bcol0 = (l4 * 16) ^ xorv;
  int boff[4];
  #pragma unroll
  for (int i = 0; i < 4; ++i)
    boff[i] = (wc * 64 + i * 16 + l15) * 128 + bcol0;

  // ---- A fragment global base: row = bm + wr*64 + mf*16 + l15, k = kt*64+sk*32+l4*8
  const uint16_t* aFrag = xbf + (size_t)(bm + wr * 64 + l15) * DIM + l4 * 8;

  float tot[16], mat[16];
  #pragma unroll
  for (int i = 0; i < 16; ++i) { tot[i] = 0.f; mat[i] = 0.f; }

  for (int ch = 0; ch < NCHUNKS; ++ch) {
    const int colb = colstart + ch * CHUNK;
    const uint16_t* gB0 = rbf + (size_t)(colb + srow) * DIM + scol;

    f32x4 acc[4][4];
    const f32x4 fz = {0.f, 0.f, 0.f, 0.f};
    #pragma unroll
    for (int mi = 0; mi < 4; ++mi)
      #pragma unroll
      for (int ni = 0; ni < 4; ++ni) acc[mi][ni] = fz;

    #pragma unroll
    for (int kt = 0; kt < NKT; ++kt) {
      const int dk = kt * 64;

      // A-fragments for this K-tile: 8 direct global loads (L2-hot, no LDS)
      short8 a0[4], a1[4];
      #pragma unroll
      for (int mf = 0; mf < 4; ++mf) {
        a0[mf] = *(const short8*)(aFrag + (size_t)mf * 16 * DIM + dk);
        a1[mf] = *(const short8*)(aFrag + (size_t)mf * 16 * DIM + dk + 32);
      }

      // B staging into LDS (4 gll-writes)
      #pragma unroll
      for (int cc = 0; cc < 4; ++cc) {
        __builtin_amdgcn_global_load_lds(
            (const __attribute__((address_space(1))) void*)(gB0 + (size_t)cc * 32 * DIM + dk),
            (__attribute__((address_space(3))) void*)(sB + cc * 4096 + w * 1024),
            16, 0, 0);
      }
      __syncthreads();

      #pragma unroll
      for (int sk = 0; sk < 2; ++sk) {
        short8 bfr[4];
        #pragma unroll
        for (int i = 0; i < 4; ++i) bfr[i] = *(const short8*)(sB + (boff[i] ^ (sk << 6)));
        #pragma unroll
        for (int mi = 0; mi < 4; ++mi)
          #pragma unroll
          for (int ni = 0; ni < 4; ++ni)
            acc[mi][ni] = __builtin_amdgcn_mfma_f32_16x16x32_bf16(
                sk ? a1[mi] : a0[mi], bfr[ni], acc[mi][ni], 0, 0, 0);
      }
      __syncthreads();
    }

    // fused epilogue: e = exp(-sqrt(x2 + r2 - 2*dot)); accumulate total & match
    float r2c[4]; int cls[4];
    #pragma unroll
    for (int ni = 0; ni < 4; ++ni) {
      int cg = colb + wc * 64 + ni * 16 + l15;
      r2c[ni] = r2[cg];
      cls[ni] = yref[cg];
    }
    #pragma unroll
    for (int mi = 0; mi < 4; ++mi) {
      #pragma unroll
      for (int r = 0; r < 4; ++r) {
        int row = bm + wr * 64 + mi * 16 + l4 * 4 + r;
        float xr = x2[row];
        int   yy = y[row];
        float tsum = 0.f, msum = 0.f;
        #pragma unroll
        for (int ni = 0; ni < 4; ++ni) {
          float t = fmaf(-2.0f, acc[mi][ni][r], xr + r2c[ni]);
          t = fmaxf(t, 0.0f);
          float d = __builtin_amdgcn_sqrtf(t);
          float e = __builtin_amdgcn_exp2f(-1.44269504088896f * d);
          tsum += e;
          msum += (cls[ni] == yy) ? e : 0.0f;
        }
        tot[mi * 4 + r] += tsum;
        mat[mi * 4 + r] += msum;
      }
    }
  }

  // reduce across the 16 lanes (l15) sharing each row, then merge globally
  #pragma unroll
  for (int i = 0; i < 16; ++i) {
    float t = tot[i], m = mat[i];
    #pragma unroll
    for (int d = 1; d <= 8; d <<= 1) {
      t += __shfl_xor(t, d, 64);
      m += __shfl_xor(m, d, 64);
    }
    if (l15 == 0) {
      int row = bm + wr * 64 + (i >> 2) * 16 + l4 * 4 + (i & 3);
      atomicAdd(&totG[row], t);
      atomicAdd(&matchG[row], m);
    }
  }
}

__global__ void finalize_loss(const float* __restrict__ totG, const float* __restrict__ matchG,
                              float* __restrict__ out) {
  __shared__ float red[256];
  int t = threadIdx.x;
  float s = 0.f;
  for (int r = t; r < M_ROWS; r += 256)
    s += logf(matchG[r] / totG[r] + 1e-6f);
  red[t] = s;
  __syncthreads();
  for (int off = 128; off >= 1; off >>= 1) {
    if (t < off) red[t] += red[t + off];
    __syncthreads();
  }
  if (t == 0) out[0] = -red[0] / (float)M_ROWS;
}

extern "C" void kernel_launch(void* const* d_in, const int* in_sizes, int n_in,
                              void* d_out, int out_size, void* d_ws, size_t ws_size,
                              hipStream_t stream) {
  const float* x    = (const float*)d_in[0];
  const float* xref = (const float*)d_in[1];
  const int*   y    = (const int*)d_in[2];
  const int*   yref = (const int*)d_in[3];
  float* out = (float*)d_out;

  uint8_t* ws = (uint8_t*)d_ws;
  uint16_t* xbf   = (uint16_t*)(ws);                    //  4 MB
  uint16_t* rbf   = (uint16_t*)(ws + 4194304);          // 32 MB
  float*    x2    = (float*)(ws + 37748736);            // 16 KB
  float*    r2    = (float*)(ws + 37765120);            // 128 KB
  float*    totG  = (float*)(ws + 37896192);            // 16 KB
  float*    matchG= (float*)(ws + 37912576);            // 16 KB

  hipMemsetAsync(totG, 0, 2 * M_ROWS * sizeof(float), stream);

  prep_rows<<<M_ROWS, 256, 0, stream>>>(x, xbf, x2);
  prep_rows<<<N_REFS, 256, 0, stream>>>(xref, rbf, r2);
  ask_main<<<(M_ROWS / BM) * NSPLIT, 256, 0, stream>>>(xbf, rbf, x2, r2, y, yref, totG, matchG);
  finalize_loss<<<1, 256, 0, stream>>>(totG, matchG, out);
}

// Round 9
// 156.866 us; speedup vs baseline: 2.3865x; 2.3865x over previous
//
#include <hip/hip_runtime.h>
#include <hip/hip_bf16.h>
#include <stdint.h>

#define M_ROWS 4096
#define N_REFS 32768
#define DIM    512
#define NSPLIT 32
#define BM     128
#define CHUNK  128
#define SLICE  (N_REFS / NSPLIT)   // 1024
#define NCHUNKS (SLICE / CHUNK)    // 8
#define NKT    (DIM / 128)         // 4 K-tiles of 128 fp8 elems

typedef __attribute__((ext_vector_type(4))) int   i32x4;
typedef __attribute__((ext_vector_type(8))) int   i32x8;
typedef __attribute__((ext_vector_type(4))) float f32x4;

// fp32 -> OCP e4m3fn, RNE, saturating. Bit-exact, no builtins.
__device__ __forceinline__ uint32_t f32_to_e4m3(float f) {
  uint32_t u = __float_as_uint(f);
  uint32_t s = (u >> 24) & 0x80u;
  float a = fabsf(f);
  if (a > 448.f) a = 448.f;                  // e4m3fn has no inf; saturate
  uint32_t b;
  if (a >= 0.015625f) {                      // normal range (>= 2^-6)
    uint32_t v = __float_as_uint(a);
    v += 0x7FFFFu + ((v >> 20) & 1u);        // RNE at mantissa bit 20
    int e = (int)(v >> 23) - 127;
    uint32_t m = (v >> 20) & 7u;
    b = (uint32_t)((e + 7) << 3) | m;
    if (b > 0x7Eu) b = 0x7Eu;                // clamp to 448
  } else {
    b = (uint32_t)(a * 512.f + 0.5f);        // subnormal grid 2^-9 (m<=8 ok)
  }
  return s | b;
}

// One block per row: fp32 row -> e4m3 (packed), sum of squares in fp32 (exact).
__global__ void prep_rows_fp8(const float* __restrict__ src, uint8_t* __restrict__ dst,
                              float* __restrict__ sq) {
  int row = blockIdx.x;
  int t = threadIdx.x;                       // 256 threads, 2 elems each
  const float2* s = (const float2*)(src + (size_t)row * DIM);
  float2 v = s[t];
  uint32_t p = f32_to_e4m3(v.x) | (f32_to_e4m3(v.y) << 8);
  ((uint16_t*)(dst + (size_t)row * DIM))[t] = (uint16_t)p;
  float ss = v.x * v.x + v.y * v.y;
  #pragma unroll
  for (int d = 32; d >= 1; d >>= 1) ss += __shfl_down(ss, d, 64);
  __shared__ float wsum[4];
  int w = t >> 6, lane = t & 63;
  if (lane == 0) wsum[w] = ss;
  __syncthreads();
  if (t == 0) sq[row] = wsum[0] + wsum[1] + wsum[2] + wsum[3];
}

// R3's validated frame (128x128 tile, 4 waves 2x2, 2-barrier K-loop, fused
// epilogue) ported to MX-fp8: mfma_scale_f32_16x16x128_f8f6f4 with unit
// scales (E8M0 0x7F = 1.0). fp8 makes a 128-elem K-tile = 128B rows — the
// SAME byte geometry as R3's 64xbf16 (same XOR swizzle, same gll staging,
// same C/D layout per m127), with half the LDS bytes per FLOP and 2x the
// matrix-pipe rate (m148: 912->1628 TF on this structure family).
__global__ __launch_bounds__(256, 2) void ask_main(
    const uint8_t* __restrict__ xf8, const uint8_t* __restrict__ rf8,
    const float* __restrict__ x2, const float* __restrict__ r2,
    const int* __restrict__ y, const int* __restrict__ yref,
    float* __restrict__ totG, float* __restrict__ matchG)
{
  __shared__ unsigned char smem[32768];      // A tile 16KB | B tile 16KB
  unsigned char* sA = smem;
  unsigned char* sB = smem + 16384;

  const int tid  = threadIdx.x;
  const int w    = tid >> 6, lane = tid & 63;
  const int wr   = w >> 1,  wc   = w & 1;
  const int l15  = lane & 15, l4 = lane >> 4;

  const int bm       = blockIdx.x * BM;
  const int colstart = blockIdx.y * SLICE;

  // staging: thread covers (srow = w*8 + lane>>3 within a 32-row chunk,
  // slot = lane&7); LDS dst linear (lane*16); source col pre-permuted by the
  // read-side involution slot ^= (row&7)  [row&7 == (lane>>3)&7]  (rule #21)
  const int srow = w * 8 + (lane >> 3);
  const int scol = ((lane & 7) ^ ((lane >> 3) & 7)) * 16;   // bytes == elems
  const uint8_t* gA0 = xf8 + (size_t)(bm + srow) * DIM + scol;

  // fragment read slots: lane needs k-bytes l4*32..+31 = 16B slots {2*l4, 2*l4+1},
  // XOR'd with row&7 (== l15&7). Same zero-conflict family as R3 (measured 0).
  const int h   = l15 & 7;
  const int sl0 = ((2 * l4)     ^ h) * 16;
  const int sl1 = ((2 * l4 + 1) ^ h) * 16;
  int aoff[4], boff[4];
  #pragma unroll
  for (int i = 0; i < 4; ++i) {
    aoff[i] = (wr * 64 + i * 16 + l15) * 128;
    boff[i] = (wc * 64 + i * 16 + l15) * 128;
  }

  float tot[16], mat[16];
  #pragma unroll
  for (int i = 0; i < 16; ++i) { tot[i] = 0.f; mat[i] = 0.f; }

  for (int ch = 0; ch < NCHUNKS; ++ch) {
    const int colb = colstart + ch * CHUNK;
    const uint8_t* gB0 = rf8 + (size_t)(colb + srow) * DIM + scol;

    f32x4 acc[4][4];
    const f32x4 fz = {0.f, 0.f, 0.f, 0.f};
    #pragma unroll
    for (int mi = 0; mi < 4; ++mi)
      #pragma unroll
      for (int ni = 0; ni < 4; ++ni) acc[mi][ni] = fz;

    #pragma unroll
    for (int kt = 0; kt < NKT; ++kt) {
      const int dk = kt * 128;
      #pragma unroll
      for (int c = 0; c < 4; ++c) {
        __builtin_amdgcn_global_load_lds(
            (const __attribute__((address_space(1))) void*)(gA0 + (size_t)c * 32 * DIM + dk),
            (__attribute__((address_space(3))) void*)(sA + c * 4096 + w * 1024),
            16, 0, 0);
      }
      #pragma unroll
      for (int c = 0; c < 4; ++c) {
        __builtin_amdgcn_global_load_lds(
            (const __attribute__((address_space(1))) void*)(gB0 + (size_t)c * 32 * DIM + dk),
            (__attribute__((address_space(3))) void*)(sB + c * 4096 + w * 1024),
            16, 0, 0);
      }
      __syncthreads();

      // B fragments (held across the mi loop), then stream A per mi
      i32x8 bfr[4];
      #pragma unroll
      for (int ni = 0; ni < 4; ++ni) {
        i32x4 lo = *(const i32x4*)(sB + boff[ni] + sl0);
        i32x4 hi = *(const i32x4*)(sB + boff[ni] + sl1);
        bfr[ni] = __builtin_shufflevector(lo, hi, 0, 1, 2, 3, 4, 5, 6, 7);
      }
      #pragma unroll
      for (int mi = 0; mi < 4; ++mi) {
        i32x4 lo = *(const i32x4*)(sA + aoff[mi] + sl0);
        i32x4 hi = *(const i32x4*)(sA + aoff[mi] + sl1);
        i32x8 afr = __builtin_shufflevector(lo, hi, 0, 1, 2, 3, 4, 5, 6, 7);
        #pragma unroll
        for (int ni = 0; ni < 4; ++ni)
          acc[mi][ni] = __builtin_amdgcn_mfma_scale_f32_16x16x128_f8f6f4(
              afr, bfr[ni], acc[mi][ni],
              0, 0,                      // cbsz=fp8(e4m3), blgp=fp8(e4m3)
              0, 0x7F7F7F7F,             // A scales = 1.0 (E8M0 127)
              0, 0x7F7F7F7F);            // B scales = 1.0
      }
      __syncthreads();
    }

    // fused epilogue: e = exp(-sqrt(x2 + r2 - 2*dot)); accumulate total & match
    float r2c[4]; int cls[4];
    #pragma unroll
    for (int ni = 0; ni < 4; ++ni) {
      int cg = colb + wc * 64 + ni * 16 + l15;
      r2c[ni] = r2[cg];
      cls[ni] = yref[cg];
    }
    #pragma unroll
    for (int mi = 0; mi < 4; ++mi) {
      #pragma unroll
      for (int r = 0; r < 4; ++r) {
        int row = bm + wr * 64 + mi * 16 + l4 * 4 + r;
        float xr = x2[row];
        int   yy = y[row];
        float tsum = 0.f, msum = 0.f;
        #pragma unroll
        for (int ni = 0; ni < 4; ++ni) {
          float t = fmaf(-2.0f, acc[mi][ni][r], xr + r2c[ni]);
          t = fmaxf(t, 0.0f);
          float d = __builtin_amdgcn_sqrtf(t);
          float e = __builtin_amdgcn_exp2f(-1.44269504088896f * d);
          tsum += e;
          msum += (cls[ni] == yy) ? e : 0.0f;
        }
        tot[mi * 4 + r] += tsum;
        mat[mi * 4 + r] += msum;
      }
    }
  }

  // reduce across the 16 lanes (l15) sharing each row, then merge globally
  #pragma unroll
  for (int i = 0; i < 16; ++i) {
    float t = tot[i], m = mat[i];
    #pragma unroll
    for (int d = 1; d <= 8; d <<= 1) {
      t += __shfl_xor(t, d, 64);
      m += __shfl_xor(m, d, 64);
    }
    if (l15 == 0) {
      int row = bm + wr * 64 + (i >> 2) * 16 + l4 * 4 + (i & 3);
      atomicAdd(&totG[row], t);
      atomicAdd(&matchG[row], m);
    }
  }
}

__global__ void finalize_loss(const float* __restrict__ totG, const float* __restrict__ matchG,
                              float* __restrict__ out) {
  __shared__ float red[256];
  int t = threadIdx.x;
  float s = 0.f;
  for (int r = t; r < M_ROWS; r += 256)
    s += logf(matchG[r] / totG[r] + 1e-6f);
  red[t] = s;
  __syncthreads();
  for (int off = 128; off >= 1; off >>= 1) {
    if (t < off) red[t] += red[t + off];
    __syncthreads();
  }
  if (t == 0) out[0] = -red[0] / (float)M_ROWS;
}

extern "C" void kernel_launch(void* const* d_in, const int* in_sizes, int n_in,
                              void* d_out, int out_size, void* d_ws, size_t ws_size,
                              hipStream_t stream) {
  const float* x    = (const float*)d_in[0];
  const float* xref = (const float*)d_in[1];
  const int*   y    = (const int*)d_in[2];
  const int*   yref = (const int*)d_in[3];
  float* out = (float*)d_out;

  uint8_t* ws = (uint8_t*)d_ws;
  uint8_t* xf8    = ws;                                 //  2 MB
  uint8_t* rf8    = ws + 2097152;                       // 16 MB
  float*   x2     = (float*)(ws + 18874368);            // 16 KB
  float*   r2     = (float*)(ws + 18890752);            // 128 KB
  float*   totG   = (float*)(ws + 19021824);            // 16 KB
  float*   matchG = (float*)(ws + 19038208);            // 16 KB

  hipMemsetAsync(totG, 0, 2 * M_ROWS * sizeof(float), stream);

  prep_rows_fp8<<<M_ROWS, 256, 0, stream>>>(x, xf8, x2);
  prep_rows_fp8<<<N_REFS, 256, 0, stream>>>(xref, rf8, r2);
  ask_main<<<dim3(M_ROWS / BM, NSPLIT), 256, 0, stream>>>(xf8, rf8, x2, r2, y, yref, totG, matchG);
  finalize_loss<<<1, 256, 0, stream>>>(totG, matchG, out);
}

// Round 10
// 151.974 us; speedup vs baseline: 2.4633x; 1.0322x over previous
//
#include <hip/hip_runtime.h>
#include <hip/hip_bf16.h>
#include <stdint.h>

#define M_ROWS 4096
#define N_REFS 32768
#define DIM    512
#define NSPLIT 32
#define BM     128
#define CHUNK  128
#define SLICE  (N_REFS / NSPLIT)   // 1024
#define NCHUNKS (SLICE / CHUNK)    // 8
#define NKT    (DIM / 128)         // 4 K-tiles of 128 fp8 elems

typedef __attribute__((ext_vector_type(4))) int   i32x4;
typedef __attribute__((ext_vector_type(8))) int   i32x8;
typedef __attribute__((ext_vector_type(4))) float f32x4;

// fp32 -> OCP e4m3fn, RNE, saturating. Bit-exact, no builtins.
__device__ __forceinline__ uint32_t f32_to_e4m3(float f) {
  uint32_t u = __float_as_uint(f);
  uint32_t s = (u >> 24) & 0x80u;
  float a = fabsf(f);
  if (a > 448.f) a = 448.f;                  // e4m3fn has no inf; saturate
  uint32_t b;
  if (a >= 0.015625f) {                      // normal range (>= 2^-6)
    uint32_t v = __float_as_uint(a);
    v += 0x7FFFFu + ((v >> 20) & 1u);        // RNE at mantissa bit 20
    int e = (int)(v >> 23) - 127;
    uint32_t m = (v >> 20) & 7u;
    b = (uint32_t)((e + 7) << 3) | m;
    if (b > 0x7Eu) b = 0x7Eu;                // clamp to 448
  } else {
    b = (uint32_t)(a * 512.f + 0.5f);        // subnormal grid 2^-9 (m<=8 ok)
  }
  return s | b;
}

// One block per row: fp32 row -> e4m3 (packed), sum of squares in fp32 (exact).
__global__ void prep_rows_fp8(const float* __restrict__ src, uint8_t* __restrict__ dst,
                              float* __restrict__ sq) {
  int row = blockIdx.x;
  int t = threadIdx.x;                       // 256 threads, 2 elems each
  const float2* s = (const float2*)(src + (size_t)row * DIM);
  float2 v = s[t];
  uint32_t p = f32_to_e4m3(v.x) | (f32_to_e4m3(v.y) << 8);
  ((uint16_t*)(dst + (size_t)row * DIM))[t] = (uint16_t)p;
  float ss = v.x * v.x + v.y * v.y;
  #pragma unroll
  for (int d = 32; d >= 1; d >>= 1) ss += __shfl_down(ss, d, 64);
  __shared__ float wsum[4];
  int w = t >> 6, lane = t & 63;
  if (lane == 0) wsum[w] = ss;
  __syncthreads();
  if (t == 0) sq[row] = wsum[0] + wsum[1] + wsum[2] + wsum[3];
}

// MX-fp8 (unit scales) port of the R3 frame. R10 change: the write-side slot
// bijection is chosen so the two fragment reads hit slots {l4^h, (l4^h)^4}
// (64B apart) — R1/R3/R6's measured-zero-conflict pattern — instead of the
// adjacent pair {(2l4)^h, (2l4+1)^h} which measured 4 extra cyc/read (R9,
// SQ_LDS_BANK_CONFLICT 8.4e6). Staging thread at linear slot q, row r
// (h=r&7) fetches global 16B-slot g: e=q^h; g = e<4 ? 2e : 2(e&3)+1.
__global__ __launch_bounds__(256, 2) void ask_main(
    const uint8_t* __restrict__ xf8, const uint8_t* __restrict__ rf8,
    const float* __restrict__ x2, const float* __restrict__ r2,
    const int* __restrict__ y, const int* __restrict__ yref,
    float* __restrict__ totG, float* __restrict__ matchG)
{
  __shared__ unsigned char smem[32768];      // A tile 16KB | B tile 16KB
  unsigned char* sA = smem;
  unsigned char* sB = smem + 16384;

  const int tid  = threadIdx.x;
  const int w    = tid >> 6, lane = tid & 63;
  const int wr   = w >> 1,  wc   = w & 1;
  const int l15  = lane & 15, l4 = lane >> 4;

  const int bm       = blockIdx.x * BM;
  const int colstart = blockIdx.y * SLICE;

  // staging: srow = w*8 + lane>>3 (row within 32-row chunk), linear slot q = lane&7.
  // source slot g per the read-side-derived bijection (see header comment).
  const int srow = w * 8 + (lane >> 3);
  const int qsl  = lane & 7;
  const int esl  = qsl ^ (srow & 7);
  const int gsl  = (esl < 4) ? (2 * esl) : (2 * (esl & 3) + 1);
  const int scol = gsl * 16;                                  // bytes
  const uint8_t* gA0 = xf8 + (size_t)(bm + srow) * DIM + scol;

  // fragment read slots (R3's zero-conflict pair): q0 = l4^h -> k-bytes
  // [l4*32, +16); q1 = q0^4 -> k-bytes [l4*32+16, +16). h = l15&7.
  const int h   = l15 & 7;
  const int sl0 = (l4 ^ h) * 16;
  const int sl1 = sl0 ^ 64;
  int aoff[4], boff[4];
  #pragma unroll
  for (int i = 0; i < 4; ++i) {
    aoff[i] = (wr * 64 + i * 16 + l15) * 128;
    boff[i] = (wc * 64 + i * 16 + l15) * 128;
  }

  float tot[16], mat[16];
  #pragma unroll
  for (int i = 0; i < 16; ++i) { tot[i] = 0.f; mat[i] = 0.f; }

  for (int ch = 0; ch < NCHUNKS; ++ch) {
    const int colb = colstart + ch * CHUNK;
    const uint8_t* gB0 = rf8 + (size_t)(colb + srow) * DIM + scol;

    f32x4 acc[4][4];
    const f32x4 fz = {0.f, 0.f, 0.f, 0.f};
    #pragma unroll
    for (int mi = 0; mi < 4; ++mi)
      #pragma unroll
      for (int ni = 0; ni < 4; ++ni) acc[mi][ni] = fz;

    #pragma unroll
    for (int kt = 0; kt < NKT; ++kt) {
      const int dk = kt * 128;
      #pragma unroll
      for (int c = 0; c < 4; ++c) {
        __builtin_amdgcn_global_load_lds(
            (const __attribute__((address_space(1))) void*)(gA0 + (size_t)c * 32 * DIM + dk),
            (__attribute__((address_space(3))) void*)(sA + c * 4096 + w * 1024),
            16, 0, 0);
      }
      #pragma unroll
      for (int c = 0; c < 4; ++c) {
        __builtin_amdgcn_global_load_lds(
            (const __attribute__((address_space(1))) void*)(gB0 + (size_t)c * 32 * DIM + dk),
            (__attribute__((address_space(3))) void*)(sB + c * 4096 + w * 1024),
            16, 0, 0);
      }
      __syncthreads();

      // B fragments (held across the mi loop), then stream A per mi
      i32x8 bfr[4];
      #pragma unroll
      for (int ni = 0; ni < 4; ++ni) {
        i32x4 lo = *(const i32x4*)(sB + boff[ni] + sl0);
        i32x4 hi = *(const i32x4*)(sB + boff[ni] + sl1);
        bfr[ni] = __builtin_shufflevector(lo, hi, 0, 1, 2, 3, 4, 5, 6, 7);
      }
      #pragma unroll
      for (int mi = 0; mi < 4; ++mi) {
        i32x4 lo = *(const i32x4*)(sA + aoff[mi] + sl0);
        i32x4 hi = *(const i32x4*)(sA + aoff[mi] + sl1);
        i32x8 afr = __builtin_shufflevector(lo, hi, 0, 1, 2, 3, 4, 5, 6, 7);
        #pragma unroll
        for (int ni = 0; ni < 4; ++ni)
          acc[mi][ni] = __builtin_amdgcn_mfma_scale_f32_16x16x128_f8f6f4(
              afr, bfr[ni], acc[mi][ni],
              0, 0,                      // cbsz=fp8(e4m3), blgp=fp8(e4m3)
              0, 0x7F7F7F7F,             // A scales = 1.0 (E8M0 127)
              0, 0x7F7F7F7F);            // B scales = 1.0
      }
      __syncthreads();
    }

    // fused epilogue: e = exp(-sqrt(x2 + r2 - 2*dot)); accumulate total & match
    float r2c[4]; int cls[4];
    #pragma unroll
    for (int ni = 0; ni < 4; ++ni) {
      int cg = colb + wc * 64 + ni * 16 + l15;
      r2c[ni] = r2[cg];
      cls[ni] = yref[cg];
    }
    #pragma unroll
    for (int mi = 0; mi < 4; ++mi) {
      #pragma unroll
      for (int r = 0; r < 4; ++r) {
        int row = bm + wr * 64 + mi * 16 + l4 * 4 + r;
        float xr = x2[row];
        int   yy = y[row];
        float tsum = 0.f, msum = 0.f;
        #pragma unroll
        for (int ni = 0; ni < 4; ++ni) {
          float t = fmaf(-2.0f, acc[mi][ni][r], xr + r2c[ni]);
          t = fmaxf(t, 0.0f);
          float d = __builtin_amdgcn_sqrtf(t);
          float e = __builtin_amdgcn_exp2f(-1.44269504088896f * d);
          tsum += e;
          msum += (cls[ni] == yy) ? e : 0.0f;
        }
        tot[mi * 4 + r] += tsum;
        mat[mi * 4 + r] += msum;
      }
    }
  }

  // reduce across the 16 lanes (l15) sharing each row, then merge globally
  #pragma unroll
  for (int i = 0; i < 16; ++i) {
    float t = tot[i], m = mat[i];
    #pragma unroll
    for (int d = 1; d <= 8; d <<= 1) {
      t += __shfl_xor(t, d, 64);
      m += __shfl_xor(m, d, 64);
    }
    if (l15 == 0) {
      int row = bm + wr * 64 + (i >> 2) * 16 + l4 * 4 + (i & 3);
      atomicAdd(&totG[row], t);
      atomicAdd(&matchG[row], m);
    }
  }
}

__global__ void finalize_loss(const float* __restrict__ totG, const float* __restrict__ matchG,
                              float* __restrict__ out) {
  __shared__ float red[256];
  int t = threadIdx.x;
  float s = 0.f;
  for (int r = t; r < M_ROWS; r += 256)
    s += logf(matchG[r] / totG[r] + 1e-6f);
  red[t] = s;
  __syncthreads();
  for (int off = 128; off >= 1; off >>= 1) {
    if (t < off) red[t] += red[t + off];
    __syncthreads();
  }
  if (t == 0) out[0] = -red[0] / (float)M_ROWS;
}

extern "C" void kernel_launch(void* const* d_in, const int* in_sizes, int n_in,
                              void* d_out, int out_size, void* d_ws, size_t ws_size,
                              hipStream_t stream) {
  const float* x    = (const float*)d_in[0];
  const float* xref = (const float*)d_in[1];
  const int*   y    = (const int*)d_in[2];
  const int*   yref = (const int*)d_in[3];
  float* out = (float*)d_out;

  uint8_t* ws = (uint8_t*)d_ws;
  uint8_t* xf8    = ws;                                 //  2 MB
  uint8_t* rf8    = ws + 2097152;                       // 16 MB
  float*   x2     = (float*)(ws + 18874368);            // 16 KB
  float*   r2     = (float*)(ws + 18890752);            // 128 KB
  float*   totG   = (float*)(ws + 19021824);            // 16 KB
  float*   matchG = (float*)(ws + 19038208);            // 16 KB

  hipMemsetAsync(totG, 0, 2 * M_ROWS * sizeof(float), stream);

  prep_rows_fp8<<<M_ROWS, 256, 0, stream>>>(x, xf8, x2);
  prep_rows_fp8<<<N_REFS, 256, 0, stream>>>(xref, rf8, r2);
  ask_main<<<dim3(M_ROWS / BM, NSPLIT), 256, 0, stream>>>(xf8, rf8, x2, r2, y, yref, totG, matchG);
  finalize_loss<<<1, 256, 0, stream>>>(totG, matchG, out);
}